// Round 4
// baseline (430.633 us; speedup 1.0000x reference)
//
#include <hip/hip_runtime.h>
#include <math.h>

// Problem constants (fixed by the reference file)
constexpr int G    = 256;   // N_GRAPHS
constexpr int EMB  = 64;
constexpr int ERBF = 16;

typedef __attribute__((ext_vector_type(8))) short bf16x8;
typedef __attribute__((ext_vector_type(4))) float f32x4;

// fp32 -> bf16 (round-to-nearest-even), bit-level
static __device__ __forceinline__ short bf16_rne(float f) {
    union { float f; unsigned u; } v; v.f = f;
    unsigned r = (v.u + 0x7FFFu + ((v.u >> 16) & 1u)) >> 16;
    return (short)r;
}
static __device__ __forceinline__ bf16x8 cvt8(float4 a, float4 b) {
    bf16x8 r;
    r[0] = bf16_rne(a.x); r[1] = bf16_rne(a.y);
    r[2] = bf16_rne(a.z); r[3] = bf16_rne(a.w);
    r[4] = bf16_rne(b.x); r[5] = bf16_rne(b.y);
    r[6] = bf16_rne(b.z); r[7] = bf16_rne(b.w);
    return r;
}

// ---------------------------------------------------------------------------
// Kernel 1: fold W2, W_out, W_rbf into M[64][16]:
//   M[p][k] = sum_j W2[p][j] * W_out[j] * W_rbf[k][j]
// ---------------------------------------------------------------------------
__global__ void prep_M_kernel(const float* __restrict__ W2,
                              const float* __restrict__ W_rbf,
                              const float* __restrict__ W_out,
                              float* __restrict__ M) {
    int t = blockIdx.x * blockDim.x + threadIdx.x;
    if (t >= EMB * ERBF) return;
    int p = t >> 4;
    int k = t & 15;
    float acc = 0.f;
    for (int j = 0; j < EMB; ++j)
        acc = fmaf(W2[p * EMB + j] * W_out[j], W_rbf[k * EMB + j], acc);
    M[p * ERBF + k] = acc;
}

// ---------------------------------------------------------------------------
// Raw (un-converted) per-tile load set, double-buffered in registers so the
// NEXT tile's global loads are in flight during this tile's compute tail.
// ---------------------------------------------------------------------------
struct Raw {
    float4 a0, a1, a2, a3;   // edge_emb row slice (32B x2 per lane)
    float4 r0, r1;           // rbf slice (q&1 dedup; zeroed at use for q>=2)
    int    es;               // edge_src (owner lanes only)
    float  dx, dy, dz;       // dvec (owner lanes only)
};

static __device__ __forceinline__ Raw load_tile(
    const float* __restrict__ edge_emb, const float* __restrict__ rbf,
    const int* __restrict__ edge_src, const float* __restrict__ dvec,
    long base, long nem1, int col, int q, int qq, bool owner, long eoff_own)
{
    Raw t;
    long er = base + col; er = (er > nem1) ? nem1 : er;
    const float* rowp = edge_emb + (size_t)er * EMB;
    const float4* pa = (const float4*)(rowp + q * 8);
    t.a0 = pa[0]; t.a1 = pa[1];
    const float4* pb = (const float4*)(rowp + 32 + q * 8);
    t.a2 = pb[0]; t.a3 = pb[1];
    const float4* pr = (const float4*)(rbf + (size_t)er * ERBF + qq * 8);
    t.r0 = pr[0]; t.r1 = pr[1];
    t.es = 0; t.dx = 0.f; t.dy = 0.f; t.dz = 0.f;
    if (owner) {
        long eo = base + eoff_own; eo = (eo > nem1) ? nem1 : eo;
        t.es = edge_src[eo];
        size_t de = (size_t)eo * 3;
        t.dx = dvec[de]; t.dy = dvec[de + 1]; t.dz = dvec[de + 2];
    }
    return t;
}

// ---------------------------------------------------------------------------
// Kernel 2 (MFMA, barrier-free, register-double-buffered):
//   H[16x64] = E_tile @ W1                 (8 mfma, C-layout)
//   V[16x64] = rbf_tile(K pad->32) @ M^T   (4 mfma, SAME C-layout)
//   score_e  = sum_p silu(H)[e][p]*V[e][p] (in-lane over nt, butterfly over col)
//   scatter  = score/|d| * d d^T  into per-graph LDS bins (stride 9)
// __launch_bounds__(256,2): 256-VGPR budget -> spill impossible; 8 waves/CU
// with prefetch keeps ~40KB/CU of loads in flight (need ~9KB for BW).
// ---------------------------------------------------------------------------
__global__ __launch_bounds__(256, 2) void edge_kernel(
    const float* __restrict__ edge_emb,   // [ne][64]
    const int*   __restrict__ edge_src,   // row 0 of edge_index, [ne]
    const float* __restrict__ dvec,       // [ne][3]
    const int*   __restrict__ batch,      // [n_nodes]
    const float* __restrict__ rbf,        // [ne][16]
    const float* __restrict__ W1,         // [64][64]
    const float* __restrict__ M,          // [64][16]
    float* __restrict__ partial,          // [nblk][G*8]
    int ne, int nblk)
{
    __shared__ float accs[G * 9];         // 6 sym + count, stride 9 (bank spread)

    const int tid  = threadIdx.x;
    const int w    = tid >> 6;
    const int lane = tid & 63;
    const int q    = lane >> 4;   // quad 0..3 (k-chunk)
    const int col  = lane & 15;   // m index (edge-in-tile / output col)
    const int qq   = q & 1;
    const bool owner = (col < 4);
    const long eoff_own = q * 4 + col;    // owned edge offset within tile

    for (int i = tid; i < G * 9; i += 256) accs[i] = 0.f;

    // ---- one-time: W1 fragments (B-layout: lane holds B[k=c*32+q*8+j][n]) ----
    bf16x8 w1f[4][2];
#pragma unroll
    for (int nt = 0; nt < 4; ++nt)
#pragma unroll
        for (int c = 0; c < 2; ++c) {
            bf16x8 wv;
#pragma unroll
            for (int j = 0; j < 8; ++j)
                wv[j] = bf16_rne(W1[(c * 32 + q * 8 + j) * EMB + nt * 16 + col]);
            w1f[nt][c] = wv;
        }
    // ---- M^T fragments for V = rbf @ M^T:  B[k][p] = M[p][k], k>=16 -> 0 ----
    bf16x8 mtf[4];
#pragma unroll
    for (int nt = 0; nt < 4; ++nt) {
        bf16x8 mv;
#pragma unroll
        for (int j = 0; j < 8; ++j) {
            int k = q * 8 + j;
            mv[j] = (k < ERBF) ? bf16_rne(M[(nt * 16 + col) * ERBF + k]) : (short)0;
        }
        mtf[nt] = mv;
    }
    __syncthreads();   // accs zeroed before any atomics

    const long nem1  = (long)ne - 1;
    const long estep = (long)nblk * 64;   // 4 waves x 16 edges per block
    long e0 = ((long)blockIdx.x * 4 + w) * 16;

    // ---- prologue: tile 0 loads in flight ----
    Raw cur = load_tile(edge_emb, rbf, edge_src, dvec,
                        (e0 <= nem1) ? e0 : nem1, nem1, col, q, qq, owner, eoff_own);

    for (; e0 < ne; ) {
        const long e1 = e0 + estep;
        // ---- PREFETCH next tile first: stays in flight through the tail ----
        Raw nxt = load_tile(edge_emb, rbf, edge_src, dvec,
                            (e1 <= nem1) ? e1 : e0, nem1, col, q, qq, owner, eoff_own);
        // ---- early gather issue (es was prefetched last iteration) ----
        int g = 0;
        if (owner) g = batch[cur.es];

        // ---- convert current tile to bf16 fragments ----
        const bool rowok = (e0 + col) <= nem1;
        bf16x8 af0 = cvt8(cur.a0, cur.a1);
        bf16x8 af1 = cvt8(cur.a2, cur.a3);
        bf16x8 rf  = cvt8(cur.r0, cur.r1);
        if (!rowok) {
#pragma unroll
            for (int j = 0; j < 8; ++j) { af0[j] = 0; af1[j] = 0; }
        }
        if (q >= 2 || !rowok) {
#pragma unroll
            for (int j = 0; j < 8; ++j) rf[j] = 0;
        }

        // ---- H = E @ W1 ;  V = rbf @ M^T ----
        f32x4 hacc[4], vacc[4];
#pragma unroll
        for (int nt = 0; nt < 4; ++nt) {
            f32x4 z = {0.f, 0.f, 0.f, 0.f};
            z = __builtin_amdgcn_mfma_f32_16x16x32_bf16(af0, w1f[nt][0], z, 0, 0, 0);
            z = __builtin_amdgcn_mfma_f32_16x16x32_bf16(af1, w1f[nt][1], z, 0, 0, 0);
            hacc[nt] = z;
            f32x4 zv = {0.f, 0.f, 0.f, 0.f};
            vacc[nt] = __builtin_amdgcn_mfma_f32_16x16x32_bf16(rf, mtf[nt], zv, 0, 0, 0);
        }

        // ---- score partials: lane(q,col) holds (e=q*4+r, p=nt*16+col) ----
        float sc[4];
#pragma unroll
        for (int r = 0; r < 4; ++r) {
            float acc = 0.f;
#pragma unroll
            for (int nt = 0; nt < 4; ++nt) {
                float x = hacc[nt][r];
                float s = x * __builtin_amdgcn_rcpf(1.f + __expf(-x));
                acc = fmaf(s, vacc[nt][r], acc);
            }
            sc[r] = acc;
        }
#pragma unroll
        for (int m = 1; m < 16; m <<= 1) {
#pragma unroll
            for (int r = 0; r < 4; ++r) sc[r] += __shfl_xor(sc[r], m);
        }

        // ---- geometry + scatter: owner lane (col<4) has edge q*4+col ----
        if (owner) {
            long e = e0 + eoff_own;
            if (e < ne) {
                float s  = sc[col];
                float dx = cur.dx, dy = cur.dy, dz = cur.dz;
                float nrm = sqrtf(dx * dx + dy * dy + dz * dz);
                float cc = s / nrm;
                float* a = &accs[g * 9];
                atomicAdd(a + 0, cc * dx * dx);
                atomicAdd(a + 1, cc * dx * dy);
                atomicAdd(a + 2, cc * dx * dz);
                atomicAdd(a + 3, cc * dy * dy);
                atomicAdd(a + 4, cc * dy * dz);
                atomicAdd(a + 5, cc * dz * dz);
                atomicAdd(a + 6, 1.0f);
            }
        }
        cur = nxt;
        e0  = e1;
        // no barrier: waves fully independent until the final flush
    }

    __syncthreads();
    // ---- flush per-block bins (stride 9 -> stride 8 for the reducer) ----
    float* outp = partial + (size_t)blockIdx.x * (G * 8);
    {
        int gg = tid;  // 256 threads == 256 graphs
        float* a = &accs[gg * 9];
        float4 p0 = {a[0], a[1], a[2], a[3]};
        float4 p1 = {a[4], a[5], a[6], 0.f};
        ((float4*)(outp + gg * 8))[0] = p0;
        ((float4*)(outp + gg * 8))[1] = p1;
    }
}

// ---------------------------------------------------------------------------
// Kernel 3: reduce per-block partials, divide by count, mirror to 3x3.
// ---------------------------------------------------------------------------
__global__ __launch_bounds__(256) void reduce_kernel(
    const float* __restrict__ partial, float* __restrict__ out, int nblk)
{
    int g = blockIdx.x;
    __shared__ float red[256][8];
    float loc[8];
#pragma unroll
    for (int c = 0; c < 8; ++c) loc[c] = 0.f;

    for (int b = threadIdx.x; b < nblk; b += 256) {
        const float4* p = (const float4*)(partial + (size_t)b * (G * 8) + g * 8);
        float4 v0 = p[0], v1 = p[1];
        loc[0] += v0.x; loc[1] += v0.y; loc[2] += v0.z; loc[3] += v0.w;
        loc[4] += v1.x; loc[5] += v1.y; loc[6] += v1.z; loc[7] += v1.w;
    }
#pragma unroll
    for (int c = 0; c < 8; ++c) red[threadIdx.x][c] = loc[c];
    __syncthreads();

    for (int off = 128; off >= 1; off >>= 1) {
        if (threadIdx.x < off) {
#pragma unroll
            for (int c = 0; c < 8; ++c)
                red[threadIdx.x][c] += red[threadIdx.x + off][c];
        }
        __syncthreads();
    }

    if (threadIdx.x == 0) {
        float cnt = red[0][6];
        float inv = (cnt > 0.f) ? (1.f / cnt) : 0.f;
        float xx = red[0][0] * inv, xy = red[0][1] * inv, xz = red[0][2] * inv;
        float yy = red[0][3] * inv, yz = red[0][4] * inv, zz = red[0][5] * inv;
        float* o = out + g * 9;
        o[0] = xx; o[1] = xy; o[2] = xz;
        o[3] = xy; o[4] = yy; o[5] = yz;
        o[6] = xz; o[7] = yz; o[8] = zz;
    }
}

// ---------------------------------------------------------------------------
extern "C" void kernel_launch(void* const* d_in, const int* in_sizes, int n_in,
                              void* d_out, int out_size, void* d_ws, size_t ws_size,
                              hipStream_t stream) {
    const float* edge_emb   = (const float*)d_in[0];
    const int*   edge_index = (const int*)  d_in[1];  // [2][ne], row 0 = src
    const float* dvec       = (const float*)d_in[2];
    // d_in[3] lattice: unused by the reference computation
    const int*   batch      = (const int*)  d_in[4];
    const float* rbf        = (const float*)d_in[5];
    const float* W1         = (const float*)d_in[6];
    const float* W2         = (const float*)d_in[7];
    const float* W_rbf      = (const float*)d_in[8];
    const float* W_out      = (const float*)d_in[9];
    float* out = (float*)d_out;

    int ne = in_sizes[0] / EMB;

    // ws layout: [0, 4096): M (64x16). [4096, ...): per-block partials (G*8 fl).
    float* M = (float*)d_ws;
    float* partial = (float*)((char*)d_ws + 4096);
    size_t avail = (ws_size > 4096) ? (ws_size - 4096) : 0;
    int nblk = (int)(avail / (G * 8 * sizeof(float)));
    int tiles = (ne + 63) / 64;
    if (nblk > 512)   nblk = 512;   // exactly 2 resident blocks/CU (launch_bounds
                                    // (256,2)) -> zero tail imbalance, ~30 it/wave
    if (nblk > tiles) nblk = tiles;
    if (nblk < 1)     nblk = 1;

    prep_M_kernel<<<4, 256, 0, stream>>>(W2, W_rbf, W_out, M);
    edge_kernel<<<nblk, 256, 0, stream>>>(edge_emb, edge_index, dvec, batch,
                                          rbf, W1, M, partial, ne, nblk);
    reduce_kernel<<<G, 256, 0, stream>>>(partial, out, nblk);
}